// Round 11
// baseline (206.665 us; speedup 1.0000x reference)
//
#include <hip/hip_runtime.h>

// Fused separable 11x11 gaussian + SSIM/charb/MSE, wave-streaming form.
// R16: R15 base (71.3us: STRH=64, 768 blocks = 3/CU, depth-2 register
// prefetch, single LDS row buffer per wave, COMMIT -> LOADR -> TAPS ->
// FINALIZE, literal ring/set indices, readfirstlane SGPR bases,
// launch_bounds(256,2)) + SP-ROW STAGING:
// COMMIT computes (s = x^2+y^2, p = x*y) once per element and stages a
// SECOND float2 LDS row (rb2). TAPS: 22 ds_read_b64 + 44 fmac (was 11
// reads + 77 VALU) -- removes the 33 redundant per-tap product ops.
// Unlike R11/R12 (float4/packed -> b128 quad temps -> 128-VGPR spill),
// all temps stay b64 float2 pairs, proven clean at 84 VGPR.
// Model revision (R15 null): R13's pure reorder (same instr count) lost
// 42% -> kernel is LATENCY-bound, not VALU-count-bound; VALUBusy's
// gfx94x-formula likely double-counts (SIMD-16 4cy vs gfx950 SIMD-32
// 2cy) -> real VALU util ~34%, 66% idle at the 3-waves/SIMD cap
// (3072 waves / 1024 SIMDs, decomposition-fixed). So: shorten chains,
// shrink code (interior 22-step body streams ~35KB through L1I), cut
// instrs -- this change does all three at zero spill risk.
// Tripwires: WRITE_SIZE == 49.2MB, VGPR <= ~100. If null: 72us is the
// latency floor of this decomposition; next swing = T=10 ragged tiles.
// Ring algebra: step i (u=i%11) -> h slot u; finalize at i>=10 emits row
// o=r-5 with weight GW[(u-s) mod 11] (GW symmetric); center diff
// dring[u] read 5 steps later at (u+6)%11. Out-of-range rows give h=0.

#define IMG    512
#define RAD    5
#define KW     11
#define STRH   64
#define ROWE   74                 // halo row entries (64 + 2*5)
#define PLANE  (IMG * IMG)

#define C1F  1e-4f
#define C2F  9e-4f
#define EPS2 1e-12f

#define W0 0.00102838f
#define W1 0.00759876f
#define W2 0.03600076f
#define W3 0.10936067f
#define W4 0.21300537f
#define W5 0.26601297f

__global__ __launch_bounds__(256, 2)
void CombinedLossSSIMCharbMSE_81372450390186_kernel(
    const float* __restrict__ pred,
    const float* __restrict__ target,
    float* __restrict__ out)
{
    const float GW[KW] = {W0, W1, W2, W3, W4, W5, W4, W3, W2, W1, W0};

    __shared__ float2 rb [4 * ROWE];  // xy row per wave, 2368 B
    __shared__ float2 rb2[4 * ROWE];  // (s,p) row per wave, 2368 B

    const int lane = threadIdx.x & 63;
    // Wave id, forced into an SGPR: everything derived below is uniform.
    const int wid = __builtin_amdgcn_readfirstlane(
        (int)((blockIdx.x << 2) | (threadIdx.x >> 6)));
    const int wav   = wid & 3;                  // wave slot in block (SGPR)
    const int plane = wid >> 6;                 // 64 waves per plane
    const int tile  = (wid >> 3) & 7;           // 8 row-tiles of 64
    const int strip = wid & 7;                  // 8 col-strips of 64
    const int col0 = strip << 6;                // SGPR
    const int row0 = tile << 6;                 // SGPR
    const int pbase = plane * PLANE;            // SGPR

    // Column geometry (constant across rows). Entry e <-> col col0-5+e.
    const int  cA  = col0 - RAD + lane;         // entries 0..63 (VGPR)
    const bool okA = (cA >= 0) & (cA < IMG);
    const int  cAc = min(max(cA, 0), IMG - 1);
    const int  cB  = col0 + 59 + lane;          // entries 64..73 (lanes 0..9)
    const bool okB = cB < IMG;
    const int  cBc = min(cB, IMG - 1);
    const bool doB = lane < 10;

    const int wb = wav * ROWE;                  // LDS row base (SGPR)

    float hrx[KW], hry[KW], hrs[KW], hrp[KW], dring[KW];
#pragma unroll
    for (int s = 0; s < KW; ++s) {
        hrx[s] = 0.f; hry[s] = 0.f; hrs[s] = 0.f; hrp[s] = 0.f; dring[s] = 0.f;
    }

    // Two prefetch register sets (depth 2), ping-ponged by step parity.
    float pA0 = 0.f, tA0 = 0.f, pB0 = 0.f, tB0 = 0.f;
    float pA1 = 0.f, tA1 = 0.f, pB1 = 0.f, tB1 = 0.f;

#define LOADR(ss, rr) do {                                                  \
        const int _b = pbase + (rr) * IMG;      /* SGPR arithmetic */       \
        pA##ss = pred[_b + cAc];                                            \
        tA##ss = target[_b + cAc];                                          \
        if (doB) {                                                          \
            pB##ss = pred[_b + cBc];                                        \
            tB##ss = target[_b + cBc];                                      \
        }                                                                   \
    } while (0)

    // Mask at commit; stage xy AND (s,p) rows (s,p from masked values).
#define COMMITR(ss) do {                                                    \
        const float _mx = okA ? pA##ss : 0.f;                               \
        const float _my = okA ? tA##ss : 0.f;                               \
        rb [wb + lane] = make_float2(_mx, _my);                             \
        rb2[wb + lane] =                                                    \
            make_float2(fmaf(_mx, _mx, _my * _my), _mx * _my);              \
        if (doB) {                                                          \
            const float _bx = okB ? pB##ss : 0.f;                           \
            const float _by = okB ? tB##ss : 0.f;                           \
            rb [wb + 64 + lane] = make_float2(_bx, _by);                    \
            rb2[wb + 64 + lane] =                                           \
                make_float2(fmaf(_bx, _bx, _by * _by), _bx * _by);          \
        }                                                                   \
        __builtin_amdgcn_wave_barrier();  /* keep write->read order */      \
    } while (0)

#define TAPS(uu) do {                                                       \
        float _hx = 0.f, _hy = 0.f, _hs = 0.f, _hp = 0.f;                   \
        float2 _c5 = make_float2(0.f, 0.f);                                 \
        _Pragma("unroll")                                                   \
        for (int _d = 0; _d < KW; ++_d) {                                   \
            const float2 _t  = rb [wb + lane + _d];                         \
            const float2 _sp = rb2[wb + lane + _d];                         \
            if (_d == RAD) _c5 = _t;                                        \
            const float _w = GW[_d];                                        \
            _hx = fmaf(_w, _t.x,  _hx);                                     \
            _hy = fmaf(_w, _t.y,  _hy);                                     \
            _hs = fmaf(_w, _sp.x, _hs);                                     \
            _hp = fmaf(_w, _sp.y, _hp);                                     \
        }                                                                   \
        hrx[uu] = _hx; hry[uu] = _hy; hrs[uu] = _hs; hrp[uu] = _hp;         \
        dring[uu] = _c5.x - _c5.y;     /* center diff, used at step i+5 */  \
    } while (0)

#define ZERO_H(uu) do {                                                     \
        hrx[uu] = 0.f; hry[uu] = 0.f; hrs[uu] = 0.f; hrp[uu] = 0.f;         \
    } while (0)

#define FINALIZE(uu, oo) do {                                               \
        float _vx = 0.f, _vy = 0.f, _vs = 0.f, _vp = 0.f;                   \
        _Pragma("unroll")                                                   \
        for (int _s = 0; _s < KW; ++_s) {                                   \
            const float _w = GW[((uu) - _s + KW) % KW];                     \
            _vx = fmaf(_w, hrx[_s], _vx);                                   \
            _vy = fmaf(_w, hry[_s], _vy);                                   \
            _vs = fmaf(_w, hrs[_s], _vs);                                   \
            _vp = fmaf(_w, hrp[_s], _vp);                                   \
        }                                                                   \
        const float _mxy = _vx * _vy;                                       \
        const float _mu2 = fmaf(_vx, _vx, _vy * _vy);                       \
        const float _A1 = fmaf(2.f, _mxy, C1F);                             \
        const float _A2 = fmaf(2.f, _vp - _mxy, C2F);                       \
        const float _B1 = _mu2 + C1F;                                       \
        const float _B2 = (_vs - _mu2) + C2F;                               \
        const float _ssim = (_A1 * _A2) * __builtin_amdgcn_rcpf(_B1 * _B2); \
        const float _dd = dring[((uu) + 6) % KW];  /* written step i-5 */   \
        const float _ch = __builtin_amdgcn_sqrtf(fmaf(_dd, _dd, EPS2));     \
        out[pbase + (oo) * IMG + col0 + lane] =                             \
            fmaf(0.3f, _ch, fmaf(2.0f, _dd * _dd, 0.6f * (1.f - _ssim)));   \
    } while (0)

    // ---- init prefetch: rows row0-5 (set0), row0-4 (set1) ----------------
    if (row0 > 0) { LOADR(0, row0 - 5); LOADR(1, row0 - 4); }

    // ---- prologue: steps i = 0..10 (u = i, set = i&1), r = row0-5+i ------
#define STEP_PRO(uu, ss) do {                                               \
        const bool _inr = (row0 - RAD + (uu)) >= 0;      /* wave-uniform */ \
        if (_inr) COMMITR(ss);                                              \
        if ((row0 - 3 + (uu)) >= 0) LOADR(ss, row0 - 3 + (uu));             \
        if (_inr) TAPS(uu); else ZERO_H(uu);                                \
    } while (0)

    STEP_PRO(0, 0); STEP_PRO(1, 1); STEP_PRO(2, 0); STEP_PRO(3, 1);
    STEP_PRO(4, 0); STEP_PRO(5, 1); STEP_PRO(6, 0); STEP_PRO(7, 1);
    STEP_PRO(8, 0); STEP_PRO(9, 1); STEP_PRO(10, 0);
    FINALIZE(10, row0);                    // first output row at i = 10

    // ---- block A: steps i = 11..21 (u = m, set = (m+1)&1), r = row0+6+m --
#define STEP_A(m, ss) do {                                                  \
        COMMITR(ss);                                                        \
        LOADR(ss, row0 + 8 + (m));                                          \
        TAPS(m);                                                            \
        FINALIZE(m, row0 + 1 + (m));                                        \
    } while (0)

    STEP_A(0, 1); STEP_A(1, 0); STEP_A(2, 1); STEP_A(3, 0); STEP_A(4, 1);
    STEP_A(5, 0); STEP_A(6, 1); STEP_A(7, 0); STEP_A(8, 1); STEP_A(9, 0);
    STEP_A(10, 1);
#undef STEP_A

    // ---- interior loop: j = 0,1; 22 steps each (i = 22+22j+t) ------------
    // u = t%11, set = t&1 (both literal); r = rbase+t; o = r-5.
    for (int j = 0; j < 2; ++j) {
        const int rbase = row0 + 17 + 22 * j;
#define STEP_I(t, uu, ss) do {                                              \
        COMMITR(ss);                                                        \
        LOADR(ss, rbase + (t) + 2);                                         \
        TAPS(uu);                                                           \
        FINALIZE(uu, rbase + (t) - 5);                                      \
    } while (0)
        STEP_I(0, 0, 0);   STEP_I(1, 1, 1);   STEP_I(2, 2, 0);
        STEP_I(3, 3, 1);   STEP_I(4, 4, 0);   STEP_I(5, 5, 1);
        STEP_I(6, 6, 0);   STEP_I(7, 7, 1);   STEP_I(8, 8, 0);
        STEP_I(9, 9, 1);   STEP_I(10, 10, 0); STEP_I(11, 0, 1);
        STEP_I(12, 1, 0);  STEP_I(13, 2, 1);  STEP_I(14, 3, 0);
        STEP_I(15, 4, 1);  STEP_I(16, 5, 0);  STEP_I(17, 6, 1);
        STEP_I(18, 7, 0);  STEP_I(19, 8, 1);  STEP_I(20, 9, 0);
        STEP_I(21, 10, 1);
#undef STEP_I
    }

    // ---- epilogue: steps i = 66..73 (u = m, set = m&1), r = row0+61+m ----
#define STEP_E(m, ss) do {                                                  \
        const bool _inr = (row0 + 61 + (m)) < IMG;       /* wave-uniform */ \
        if (_inr) COMMITR(ss);                                              \
        if (((m) < 6) && (row0 + 63 + (m)) < IMG)                           \
            LOADR(ss, row0 + 63 + (m));                                     \
        if (_inr) TAPS(m); else ZERO_H(m);                                  \
        FINALIZE(m, row0 + 56 + (m));                                       \
    } while (0)

    STEP_E(0, 0); STEP_E(1, 1); STEP_E(2, 0); STEP_E(3, 1);
    STEP_E(4, 0); STEP_E(5, 1); STEP_E(6, 0); STEP_E(7, 1);
#undef STEP_E
#undef STEP_PRO
#undef FINALIZE
#undef ZERO_H
#undef TAPS
#undef COMMITR
#undef LOADR
}

extern "C" void kernel_launch(void* const* d_in, const int* in_sizes, int n_in,
                              void* d_out, int out_size, void* d_ws, size_t ws_size,
                              hipStream_t stream) {
    const float* pred = (const float*)d_in[0];
    const float* target = (const float*)d_in[1];
    float* out = (float*)d_out;
    const int planes = in_sizes[0] / PLANE;     // 48

    // 64 waves per plane (8 strips x 8 tiles of 64 rows), 4 waves/block.
    dim3 grid(planes * 16);                     // 768 blocks = 3 per CU
    CombinedLossSSIMCharbMSE_81372450390186_kernel<<<grid, dim3(256), 0, stream>>>(
        pred, target, out);
}